// Round 1
// baseline (304.635 us; speedup 1.0000x reference)
//
#include <hip/hip_runtime.h>
#include <cstdint>

#define B_DIM 4
#define C_DIM 512
#define T_DIM 400
#define KW 31
#define TOUT 400
#define PADL 15

// ---------------- host threefry2x32 (key-chain computation, pure CPU) --------
static inline uint32_t h_rotl32(uint32_t x, int d){ return (x<<d)|(x>>(32-d)); }

static void h_threefry2x32(uint32_t k0, uint32_t k1, uint32_t x0, uint32_t x1,
                           uint32_t* o0, uint32_t* o1){
  uint32_t ks2 = k0 ^ k1 ^ 0x1BD11BDAu;
  uint32_t ks[3] = {k0, k1, ks2};
  const int rotA[4] = {13,15,26,6};
  const int rotB[4] = {17,29,16,24};
  uint32_t v0 = x0 + k0, v1 = x1 + k1;
  for (int r = 0; r < 5; ++r){
    const int* rot = (r & 1) ? rotB : rotA;
    for (int q = 0; q < 4; ++q){
      v0 += v1; v1 = h_rotl32(v1, rot[q]); v1 ^= v0;
    }
    v0 += ks[(r+1)%3];
    v1 += ks[(r+2)%3] + (uint32_t)(r+1);
  }
  *o0 = v0; *o1 = v1;
}

// ---------------- device threefry2x32 specialized for counts (0, j) ---------
#define TF_ROUND(v0,v1,R) { v0 += v1; v1 = (v1<<R)|(v1>>(32-R)); v1 ^= v0; }

__device__ __forceinline__ uint32_t threefry_xor(uint32_t k0, uint32_t k1, uint32_t x1){
  uint32_t ks2 = k0 ^ k1 ^ 0x1BD11BDAu;
  uint32_t v0 = k0;          // x0 = 0
  uint32_t v1 = x1 + k1;
  TF_ROUND(v0,v1,13) TF_ROUND(v0,v1,15) TF_ROUND(v0,v1,26) TF_ROUND(v0,v1,6)
  v0 += k1;  v1 += ks2 + 1u;
  TF_ROUND(v0,v1,17) TF_ROUND(v0,v1,29) TF_ROUND(v0,v1,16) TF_ROUND(v0,v1,24)
  v0 += ks2; v1 += k0 + 2u;
  TF_ROUND(v0,v1,13) TF_ROUND(v0,v1,15) TF_ROUND(v0,v1,26) TF_ROUND(v0,v1,6)
  v0 += k0;  v1 += k1 + 3u;
  TF_ROUND(v0,v1,17) TF_ROUND(v0,v1,29) TF_ROUND(v0,v1,16) TF_ROUND(v0,v1,24)
  v0 += k1;  v1 += ks2 + 4u;
  TF_ROUND(v0,v1,13) TF_ROUND(v0,v1,15) TF_ROUND(v0,v1,26) TF_ROUND(v0,v1,6)
  v0 += ks2; v1 += k0 + 5u;
  return v0 ^ v1;            // partitionable 32-bit path: bits1 ^ bits2
}

// ---------------- XLA ErfInv32 (Giles 2012, w = -log1p(-x^2)) ---------------
__device__ __forceinline__ float erfinv_xla(float x){
  float w = -log1pf(-x*x);
  float p;
  if (w < 5.0f){
    w = w - 2.5f;
    p =              2.81022636e-08f;
    p = fmaf(p, w,   3.43273939e-07f);
    p = fmaf(p, w,  -3.5233877e-06f);
    p = fmaf(p, w,  -4.39150654e-06f);
    p = fmaf(p, w,   0.00021858087f);
    p = fmaf(p, w,  -0.00125372503f);
    p = fmaf(p, w,  -0.00417768164f);
    p = fmaf(p, w,   0.246640727f);
    p = fmaf(p, w,   1.50140941f);
  } else {
    w = sqrtf(w) - 3.0f;
    p =             -0.000200214257f;
    p = fmaf(p, w,   0.000100950558f);
    p = fmaf(p, w,   0.00134934322f);
    p = fmaf(p, w,  -0.00367342844f);
    p = fmaf(p, w,   0.00573950773f);
    p = fmaf(p, w,  -0.0076224613f);
    p = fmaf(p, w,   0.00943887047f);
    p = fmaf(p, w,   1.00167406f);
    p = fmaf(p, w,   2.83297682f);
  }
  return p * x;
}

__global__ __launch_bounds__(256) void memristor_conv1d_kernel(
    const float* __restrict__ x,        // (B, C, T)
    const float* __restrict__ poly_low, // (2, 2, 7)
    const float* __restrict__ poly_high,// (2, 2, 6)
    const float* __restrict__ r,        // (2, 2, C, K)
    const float* __restrict__ bias,     // (C,)
    float* __restrict__ out,            // (B, C, TOUT)
    uint32_t nk00a, uint32_t nk00b, uint32_t nk01a, uint32_t nk01b,
    uint32_t nk10a, uint32_t nk10b, uint32_t nk11a, uint32_t nk11b)
{
  const int tid = blockIdx.x * blockDim.x + threadIdx.x;
  if (tid >= C_DIM * TOUT) return;
  const int c = tid / TOUT;
  const int t = tid - c * TOUT;

  // hoist polynomial coefficients (uniform -> scalar loads)
  float PL[2][2][7];
  float PH[2][2][6];
  #pragma unroll
  for (int i = 0; i < 2; ++i)
    #pragma unroll
    for (int s = 0; s < 2; ++s){
      #pragma unroll
      for (int j = 0; j < 7; ++j) PL[i][s][j] = poly_low[(i*2+s)*7 + j];
      #pragma unroll
      for (int j = 0; j < 6; ++j) PH[i][s][j] = poly_high[(i*2+s)*6 + j];
    }

  const uint32_t nkA[2][2] = {{nk00a, nk01a}, {nk10a, nk11a}};
  const uint32_t nkB[2][2] = {{nk00b, nk01b}, {nk10b, nk11b}};

  const float KJ  = 1.6567788e-28f;   // 4*KBT*BW  (f32 of double product)
  const float KS  = 5.4365637e-08f;   // 2*E*BW
  const float EPSF = 1e-12f;
  const float LO  = -0.99999994f;     // nextafter(-1,0)
  const float SQRT2 = 1.41421356f;    // f32(sqrt(2)) = 0x3FB504F3

  float acc[B_DIM][2][2];
  #pragma unroll
  for (int b = 0; b < B_DIM; ++b)
    #pragma unroll
    for (int i = 0; i < 2; ++i){ acc[b][i][0] = 0.0f; acc[b][i][1] = 0.0f; }

  for (int k = 0; k < KW; ++k){
    const int time = t + k - PADL;
    float w[B_DIM], invw[B_DIM];
    #pragma unroll
    for (int b = 0; b < B_DIM; ++b){
      float xv = 0.0f;
      if (time >= 0 && time < T_DIM) xv = x[(b*C_DIM + c)*T_DIM + time];
      // DAC fake-quant forward: clip(rne(x*128), -128, 128) * (1/128), then *VMAX
      float q = rintf(xv * 128.0f);
      q = fminf(fmaxf(q, -128.0f), 128.0f);
      float v = (q * 0.0078125f) * 0.6f;
      w[b] = v;
      invw[b] = 1.0f / (fabsf(v) + EPSF);
    }

    const uint32_t j = (uint32_t)((t * C_DIM + c) * KW + k);

    #pragma unroll
    for (int i = 0; i < 2; ++i){
      #pragma unroll
      for (int s = 0; s < 2; ++s){
        // jax.random.normal bits (threefry partitionable, 32-bit)
        const uint32_t bits = threefry_xor(nkA[i][s], nkB[i][s], j);
        const float u1 = __uint_as_float((bits >> 9) | 0x3f800000u) - 1.0f; // [0,1)
        const float uu = fmaxf(LO, fmaf(u1, 2.0f, LO));                     // [lo,1)
        const float noise = SQRT2 * erfinv_xla(uu);

        const float rr = r[((i*2 + s)*C_DIM + c)*KW + k];
        const float one_m_rr = 1.0f - rr;

        #pragma unroll
        for (int b = 0; b < B_DIM; ++b){
          const float wv = w[b];
          // polyval ascending, Horner from c6..c0 / c5..c0
          float low = PL[i][s][6];
          low = fmaf(low, wv, PL[i][s][5]);
          low = fmaf(low, wv, PL[i][s][4]);
          low = fmaf(low, wv, PL[i][s][3]);
          low = fmaf(low, wv, PL[i][s][2]);
          low = fmaf(low, wv, PL[i][s][1]);
          low = fmaf(low, wv, PL[i][s][0]);
          float high = PH[i][s][5];
          high = fmaf(high, wv, PH[i][s][4]);
          high = fmaf(high, wv, PH[i][s][3]);
          high = fmaf(high, wv, PH[i][s][2]);
          high = fmaf(high, wv, PH[i][s][1]);
          high = fmaf(high, wv, PH[i][s][0]);

          const float raw = low * one_m_rr + high * rr;
          const float ar = fabsf(raw);
          const float sigma = sqrtf(KJ * ar * invw[b] + KS * ar);
          acc[b][i][s] += raw + noise * sigma;
        }
      }
    }
  }

  const float bv = bias[c];
  #pragma unroll
  for (int b = 0; b < B_DIM; ++b){
    float o = 0.0f;
    #pragma unroll
    for (int i = 0; i < 2; ++i){
      const float pair = acc[b][i][0] - acc[b][i][1];
      // ADC fake-quant forward: clip(rne(x*8020*256), +-131072) * (1/256)
      const float xq = pair * 8020.0f;
      float q = rintf(xq * 256.0f);
      q = fminf(fmaxf(q, -131072.0f), 131072.0f);
      const float fq = q * 0.00390625f;
      o += fq * ((i == 0) ? 2.0f : 1.0f);   // 2^bit, bit = 1 then 0
    }
    out[(b*C_DIM + c)*TOUT + t] = o + bv;   // OUTPUT_FACTOR = 1
  }
}

extern "C" void kernel_launch(void* const* d_in, const int* in_sizes, int n_in,
                              void* d_out, int out_size, void* d_ws, size_t ws_size,
                              hipStream_t stream) {
  const float* x         = (const float*)d_in[0];
  const float* poly_low  = (const float*)d_in[1];
  const float* poly_high = (const float*)d_in[2];
  const float* r         = (const float*)d_in[3];
  const float* bias      = (const float*)d_in[4];
  float* out             = (float*)d_out;

  // key chain: key = jax.random.key(42) -> 4x (key, nk) = split(key)
  // partitionable/foldlike split: newkey = TF(key,(0,0)), nk = TF(key,(0,1))
  uint32_t ck0 = 0u, ck1 = 42u;
  uint32_t nk[4][2];
  for (int n = 0; n < 4; ++n){
    uint32_t a0, a1, b0, b1;
    h_threefry2x32(ck0, ck1, 0u, 0u, &a0, &a1);  // keys[0] -> new key
    h_threefry2x32(ck0, ck1, 0u, 1u, &b0, &b1);  // keys[1] -> nk
    nk[n][0] = b0; nk[n][1] = b1;
    ck0 = a0; ck1 = a1;
  }

  const int total = C_DIM * TOUT;
  dim3 block(256);
  dim3 grid((total + 255) / 256);
  hipLaunchKernelGGL(memristor_conv1d_kernel, grid, block, 0, stream,
                     x, poly_low, poly_high, r, bias, out,
                     nk[0][0], nk[0][1], nk[1][0], nk[1][1],
                     nk[2][0], nk[2][1], nk[3][0], nk[3][1]);
}

// Round 2
// 115.817 us; speedup vs baseline: 2.6303x; 2.6303x over previous
//
#include <hip/hip_runtime.h>
#include <cstdint>

#define C_DIM 512
#define T_DIM 400
#define KW 31
#define TOUT 400
#define PADL 15
#define PPB 128   // (c,t) pairs per block; block = 256 threads = 2 k-halves

// ---------------- host threefry2x32 (key-chain computation, pure CPU) --------
static inline uint32_t h_rotl32(uint32_t x, int d){ return (x<<d)|(x>>(32-d)); }

static void h_threefry2x32(uint32_t k0, uint32_t k1, uint32_t x0, uint32_t x1,
                           uint32_t* o0, uint32_t* o1){
  uint32_t ks2 = k0 ^ k1 ^ 0x1BD11BDAu;
  uint32_t ks[3] = {k0, k1, ks2};
  const int rotA[4] = {13,15,26,6};
  const int rotB[4] = {17,29,16,24};
  uint32_t v0 = x0 + k0, v1 = x1 + k1;
  for (int r = 0; r < 5; ++r){
    const int* rot = (r & 1) ? rotB : rotA;
    for (int q = 0; q < 4; ++q){
      v0 += v1; v1 = h_rotl32(v1, rot[q]); v1 ^= v0;
    }
    v0 += ks[(r+1)%3];
    v1 += ks[(r+2)%3] + (uint32_t)(r+1);
  }
  *o0 = v0; *o1 = v1;
}

// ---------------- device threefry, 4 independent streams in lockstep --------
template<int R>
__device__ __forceinline__ void tfr4(uint32_t v0[4], uint32_t v1[4]){
  #pragma unroll
  for (int n = 0; n < 4; ++n){
    v0[n] += v1[n];
    v1[n] = (v1[n] << R) | (v1[n] >> (32 - R));   // -> v_alignbit_b32
    v1[n] ^= v0[n];
  }
}

__device__ __forceinline__ void tfinj4(uint32_t v0[4], uint32_t v1[4],
                                       const uint32_t a[4], const uint32_t b[4],
                                       uint32_t cadd){
  #pragma unroll
  for (int n = 0; n < 4; ++n){ v0[n] += a[n]; v1[n] += b[n] + cadd; }
}

__device__ __forceinline__ void threefry_xor4(const uint32_t ka[4], const uint32_t kb[4],
                                              uint32_t j, uint32_t out[4]){
  uint32_t ks2[4], v0[4], v1[4];
  #pragma unroll
  for (int n = 0; n < 4; ++n){
    ks2[n] = ka[n] ^ kb[n] ^ 0x1BD11BDAu;
    v0[n] = ka[n];            // x0 = 0
    v1[n] = j + kb[n];        // x1 = j
  }
  tfr4<13>(v0,v1); tfr4<15>(v0,v1); tfr4<26>(v0,v1); tfr4<6>(v0,v1);
  tfinj4(v0,v1,kb,ks2,1u);
  tfr4<17>(v0,v1); tfr4<29>(v0,v1); tfr4<16>(v0,v1); tfr4<24>(v0,v1);
  tfinj4(v0,v1,ks2,ka,2u);
  tfr4<13>(v0,v1); tfr4<15>(v0,v1); tfr4<26>(v0,v1); tfr4<6>(v0,v1);
  tfinj4(v0,v1,ka,kb,3u);
  tfr4<17>(v0,v1); tfr4<29>(v0,v1); tfr4<16>(v0,v1); tfr4<24>(v0,v1);
  tfinj4(v0,v1,kb,ks2,4u);
  tfr4<13>(v0,v1); tfr4<15>(v0,v1); tfr4<26>(v0,v1); tfr4<6>(v0,v1);
  tfinj4(v0,v1,ks2,ka,5u);
  #pragma unroll
  for (int n = 0; n < 4; ++n) out[n] = v0[n] ^ v1[n];
}

// -------- XLA ErfInv32 (Giles 2012), raw-rate v_log / v_sqrt ----------------
__device__ __forceinline__ float erfinv_fast(float x){
  // log1p(-x^2) == log((1-x)(1+x)); factored form avoids cancellation
  float w = -0.69314718f * __builtin_amdgcn_logf((1.0f - x) * (1.0f + x));
  float p;
  if (w < 5.0f){                       // ~99.7% of lanes: usually whole-wave
    w = w - 2.5f;
    p =              2.81022636e-08f;
    p = fmaf(p, w,   3.43273939e-07f);
    p = fmaf(p, w,  -3.5233877e-06f);
    p = fmaf(p, w,  -4.39150654e-06f);
    p = fmaf(p, w,   0.00021858087f);
    p = fmaf(p, w,  -0.00125372503f);
    p = fmaf(p, w,  -0.00417768164f);
    p = fmaf(p, w,   0.246640727f);
    p = fmaf(p, w,   1.50140941f);
  } else {
    w = __builtin_amdgcn_sqrtf(w) - 3.0f;
    p =             -0.000200214257f;
    p = fmaf(p, w,   0.000100950558f);
    p = fmaf(p, w,   0.00134934322f);
    p = fmaf(p, w,  -0.00367342844f);
    p = fmaf(p, w,   0.00573950773f);
    p = fmaf(p, w,  -0.0076224613f);
    p = fmaf(p, w,   0.00943887047f);
    p = fmaf(p, w,   1.00167406f);
    p = fmaf(p, w,   2.83297682f);
  }
  return p * x;
}

__global__ __launch_bounds__(256) void memristor_conv1d_kernel(
    const float* __restrict__ x,        // (B=4, C, T)
    const float* __restrict__ poly_low, // (2, 2, 7)
    const float* __restrict__ poly_high,// (2, 2, 6)
    const float* __restrict__ r,        // (2, 2, C, K)
    const float* __restrict__ bias,     // (C,)
    float* __restrict__ out,            // (B, C, TOUT)
    uint32_t nk0a, uint32_t nk0b, uint32_t nk1a, uint32_t nk1b,
    uint32_t nk2a, uint32_t nk2b, uint32_t nk3a, uint32_t nk3b)
{
  // LUT: per (is, qidx): (low(w), high(w)-low(w)) for the 257 DAC levels
  __shared__ float2 lut[4][257];
  __shared__ float partial[PPB][17];    // stride 17: conflict-free (17 odd)

  const int tid = threadIdx.x;

  // ---- build LUT (once per block) ----
  for (int idx = tid; idx < 4 * 257; idx += 256){
    const int is = idx / 257;
    const int qi = idx - is * 257;
    const float q = (float)(qi - 128);
    const float w = (q * 0.0078125f) * 0.6f;   // bit-exact DAC value
    const float* pl = poly_low  + is * 7;
    const float* ph = poly_high + is * 6;
    float lo = pl[6];
    lo = fmaf(lo, w, pl[5]); lo = fmaf(lo, w, pl[4]); lo = fmaf(lo, w, pl[3]);
    lo = fmaf(lo, w, pl[2]); lo = fmaf(lo, w, pl[1]); lo = fmaf(lo, w, pl[0]);
    float hi = ph[5];
    hi = fmaf(hi, w, ph[4]); hi = fmaf(hi, w, ph[3]); hi = fmaf(hi, w, ph[2]);
    hi = fmaf(hi, w, ph[1]); hi = fmaf(hi, w, ph[0]);
    lut[is][qi] = make_float2(lo, hi - lo);
  }
  __syncthreads();

  // ---- thread mapping: 2 threads per (c,t), split over K ----
  const int p   = tid & (PPB - 1);
  const int h   = tid >> 7;                 // 0: k=[0,16)  1: k=[16,31)
  const int gid = blockIdx.x * PPB + p;     // grid covers exactly C*TOUT
  const int c   = gid / TOUT;
  const int t   = gid - c * TOUT;
  const int k0  = h ? 16 : 0;
  const int kn  = h ? 15 : 16;

  const uint32_t ka[4] = {nk0a, nk1a, nk2a, nk3a};
  const uint32_t kb[4] = {nk0b, nk1b, nk2b, nk3b};

  float acc[4][4];                          // [b][is]
  #pragma unroll
  for (int b = 0; b < 4; ++b)
    #pragma unroll
    for (int is = 0; is < 4; ++is) acc[b][is] = 0.0f;

  for (int kk = 0; kk < kn; ++kk){
    const int k = k0 + kk;
    const int time = t + k - PADL;
    const bool inb = (time >= 0) && (time < T_DIM);

    int   qi[4];
    float jfac[4];
    #pragma unroll
    for (int b = 0; b < 4; ++b){
      float xv = inb ? x[(b * C_DIM + c) * T_DIM + time] : 0.0f;
      float q = rintf(xv * 128.0f);
      q = fminf(fmaxf(q, -128.0f), 128.0f);
      const float v = (q * 0.0078125f) * 0.6f;
      qi[b] = (int)q + 128;
      jfac[b] = fmaf(1.6567788e-28f,
                     __builtin_amdgcn_rcpf(fabsf(v) + 1e-12f),
                     5.4365637e-08f);       // johnson/|raw| + shot/|raw|
    }

    const uint32_t j = (uint32_t)((t * C_DIM + c) * KW + k);
    uint32_t bits[4];
    threefry_xor4(ka, kb, j, bits);

    float noise[4];
    #pragma unroll
    for (int is = 0; is < 4; ++is){
      const float u1 = __uint_as_float((bits[is] >> 9) | 0x3f800000u) - 1.0f;
      const float uu = fmaxf(-0.99999994f, fmaf(u1, 2.0f, -0.99999994f));
      noise[is] = 1.41421356f * erfinv_fast(uu);
    }

    #pragma unroll
    for (int is = 0; is < 4; ++is){
      const float rr = r[(is * C_DIM + c) * KW + k];
      #pragma unroll
      for (int b = 0; b < 4; ++b){
        const float2 ld = lut[is][qi[b]];
        const float raw = fmaf(ld.y, rr, ld.x);      // low + rr*(high-low)
        const float sigma = __builtin_amdgcn_sqrtf(fabsf(raw) * jfac[b]);
        acc[b][is] += raw + noise[is] * sigma;
      }
    }
  }

  // ---- combine the two k-halves through LDS ----
  if (h == 1){
    #pragma unroll
    for (int b = 0; b < 4; ++b)
      #pragma unroll
      for (int is = 0; is < 4; ++is)
        partial[p][b * 4 + is] = acc[b][is];
  }
  __syncthreads();

  if (h == 0){
    const float bv = bias[c];
    #pragma unroll
    for (int b = 0; b < 4; ++b){
      float o = 0.0f;
      #pragma unroll
      for (int i = 0; i < 2; ++i){
        const float a0 = acc[b][i*2+0] + partial[p][b*4 + i*2 + 0];
        const float a1 = acc[b][i*2+1] + partial[p][b*4 + i*2 + 1];
        const float pair = a0 - a1;
        // ADC fake-quant: clip(rne(pair*8020*256), +-131072) / 256
        float q = rintf((pair * 8020.0f) * 256.0f);
        q = fminf(fmaxf(q, -131072.0f), 131072.0f);
        o += (q * 0.00390625f) * ((i == 0) ? 2.0f : 1.0f);
      }
      out[(b * C_DIM + c) * TOUT + t] = o + bv;
    }
  }
}

extern "C" void kernel_launch(void* const* d_in, const int* in_sizes, int n_in,
                              void* d_out, int out_size, void* d_ws, size_t ws_size,
                              hipStream_t stream) {
  const float* x         = (const float*)d_in[0];
  const float* poly_low  = (const float*)d_in[1];
  const float* poly_high = (const float*)d_in[2];
  const float* r         = (const float*)d_in[3];
  const float* bias      = (const float*)d_in[4];
  float* out             = (float*)d_out;

  // key chain: key = jax.random.key(42); 4x (key, nk) = split(key)
  uint32_t ck0 = 0u, ck1 = 42u;
  uint32_t nk[4][2];
  for (int n = 0; n < 4; ++n){
    uint32_t a0, a1, b0, b1;
    h_threefry2x32(ck0, ck1, 0u, 0u, &a0, &a1);  // new key
    h_threefry2x32(ck0, ck1, 0u, 1u, &b0, &b1);  // nk
    nk[n][0] = b0; nk[n][1] = b1;
    ck0 = a0; ck1 = a1;
  }

  const int total_pairs = C_DIM * TOUT;          // 204800
  dim3 block(256);
  dim3 grid(total_pairs / PPB);                  // 1600 blocks, exact
  hipLaunchKernelGGL(memristor_conv1d_kernel, grid, block, 0, stream,
                     x, poly_low, poly_high, r, bias, out,
                     nk[0][0], nk[0][1], nk[1][0], nk[1][1],
                     nk[2][0], nk[2][1], nk[3][0], nk[3][1]);
}

// Round 3
// 109.837 us; speedup vs baseline: 2.7735x; 1.0544x over previous
//
#include <hip/hip_runtime.h>
#include <cstdint>

#define C_DIM 512
#define T_DIM 400
#define KW 31
#define TOUT 400
#define WSROW 432   // padded time index t+k in [0,430]; rounded to 432
#define TPB 128
#define PPB 64      // (c,t) pairs per block (2 k-half lanes each)

// ---------------- host threefry2x32 (key-chain computation, pure CPU) --------
static inline uint32_t h_rotl32(uint32_t x, int d){ return (x<<d)|(x>>(32-d)); }

static void h_threefry2x32(uint32_t k0, uint32_t k1, uint32_t x0, uint32_t x1,
                           uint32_t* o0, uint32_t* o1){
  uint32_t ks2 = k0 ^ k1 ^ 0x1BD11BDAu;
  uint32_t ks[3] = {k0, k1, ks2};
  const int rotA[4] = {13,15,26,6};
  const int rotB[4] = {17,29,16,24};
  uint32_t v0 = x0 + k0, v1 = x1 + k1;
  for (int r = 0; r < 5; ++r){
    const int* rot = (r & 1) ? rotB : rotA;
    for (int q = 0; q < 4; ++q){
      v0 += v1; v1 = h_rotl32(v1, rot[q]); v1 ^= v0;
    }
    v0 += ks[(r+1)%3];
    v1 += ks[(r+2)%3] + (uint32_t)(r+1);
  }
  *o0 = v0; *o1 = v1;
}

// ---------------- device threefry, 4 independent streams in lockstep --------
template<int R>
__device__ __forceinline__ void tfr4(uint32_t v0[4], uint32_t v1[4]){
  #pragma unroll
  for (int n = 0; n < 4; ++n){
    v0[n] += v1[n];
    v1[n] = (v1[n] << R) | (v1[n] >> (32 - R));   // -> v_alignbit_b32
    v1[n] ^= v0[n];
  }
}

__device__ __forceinline__ void tfinj4(uint32_t v0[4], uint32_t v1[4],
                                       const uint32_t a[4], const uint32_t b[4],
                                       uint32_t cadd){
  #pragma unroll
  for (int n = 0; n < 4; ++n){ v0[n] += a[n]; v1[n] += b[n] + cadd; }
}

__device__ __forceinline__ void threefry_xor4(const uint32_t ka[4], const uint32_t kb[4],
                                              uint32_t j, uint32_t out[4]){
  uint32_t ks2[4], v0[4], v1[4];
  #pragma unroll
  for (int n = 0; n < 4; ++n){
    ks2[n] = ka[n] ^ kb[n] ^ 0x1BD11BDAu;
    v0[n] = ka[n];            // x0 = 0
    v1[n] = j + kb[n];        // x1 = j
  }
  tfr4<13>(v0,v1); tfr4<15>(v0,v1); tfr4<26>(v0,v1); tfr4<6>(v0,v1);
  tfinj4(v0,v1,kb,ks2,1u);
  tfr4<17>(v0,v1); tfr4<29>(v0,v1); tfr4<16>(v0,v1); tfr4<24>(v0,v1);
  tfinj4(v0,v1,ks2,ka,2u);
  tfr4<13>(v0,v1); tfr4<15>(v0,v1); tfr4<26>(v0,v1); tfr4<6>(v0,v1);
  tfinj4(v0,v1,ka,kb,3u);
  tfr4<17>(v0,v1); tfr4<29>(v0,v1); tfr4<16>(v0,v1); tfr4<24>(v0,v1);
  tfinj4(v0,v1,kb,ks2,4u);
  tfr4<13>(v0,v1); tfr4<15>(v0,v1); tfr4<26>(v0,v1); tfr4<6>(v0,v1);
  tfinj4(v0,v1,ks2,ka,5u);
  #pragma unroll
  for (int n = 0; n < 4; ++n) out[n] = v0[n] ^ v1[n];
}

// -------- XLA ErfInv32 (Giles 2012), raw-rate v_log / v_sqrt ----------------
__device__ __forceinline__ float erfinv_fast(float x){
  // -log1p(-x^2) = -ln2 * log2((1-x)(1+x))
  float w = -0.69314718f * __builtin_amdgcn_logf((1.0f - x) * (1.0f + x));
  float p;
  if (w < 5.0f){
    w = w - 2.5f;
    p =              2.81022636e-08f;
    p = fmaf(p, w,   3.43273939e-07f);
    p = fmaf(p, w,  -3.5233877e-06f);
    p = fmaf(p, w,  -4.39150654e-06f);
    p = fmaf(p, w,   0.00021858087f);
    p = fmaf(p, w,  -0.00125372503f);
    p = fmaf(p, w,  -0.00417768164f);
    p = fmaf(p, w,   0.246640727f);
    p = fmaf(p, w,   1.50140941f);
  } else {
    w = __builtin_amdgcn_sqrtf(w) - 3.0f;
    p =             -0.000200214257f;
    p = fmaf(p, w,   0.000100950558f);
    p = fmaf(p, w,   0.00134934322f);
    p = fmaf(p, w,  -0.00367342844f);
    p = fmaf(p, w,   0.00573950773f);
    p = fmaf(p, w,  -0.0076224613f);
    p = fmaf(p, w,   0.00943887047f);
    p = fmaf(p, w,   1.00167406f);
    p = fmaf(p, w,   2.83297682f);
  }
  return p * x;
}

// ---------------- pre-pass: DAC-quantize x once per (c,time) ----------------
__global__ __launch_bounds__(256) void dac_prepass(
    const float* __restrict__ x, uint2* __restrict__ wsq)
{
  const int m = blockIdx.x * 256 + threadIdx.x;      // m over 512*432 exactly
  const int c  = m / WSROW;
  const int tp = m - c * WSROW;
  const int time = tp - 15;
  const bool inb = (time >= 0) && (time < T_DIM);
  uint32_t qi[4];
  #pragma unroll
  for (int b = 0; b < 4; ++b){
    float xv = inb ? x[(b * C_DIM + c) * T_DIM + time] : 0.0f;
    float q = rintf(xv * 128.0f);
    q = fminf(fmaxf(q, -128.0f), 128.0f);
    qi[b] = (uint32_t)((int)q + 128);
  }
  wsq[m] = make_uint2(qi[0] | (qi[1] << 16), qi[2] | (qi[3] << 16));
}

// ---------------- main kernel ----------------------------------------------
template<bool USE_WS>
__global__ __launch_bounds__(TPB) void memristor_main(
    const float* __restrict__ x,
    const float* __restrict__ poly_low,   // (2,2,7)
    const float* __restrict__ poly_high,  // (2,2,6)
    const float* __restrict__ r,          // (2,2,C,K)
    const float* __restrict__ bias,
    const uint2* __restrict__ wsq,        // (C, WSROW) packed u16 qi x4
    float* __restrict__ out,              // (B,C,TOUT)
    uint32_t nk0a, uint32_t nk0b, uint32_t nk1a, uint32_t nk1b,
    uint32_t nk2a, uint32_t nk2b, uint32_t nk3a, uint32_t nk3b)
{
  // row layout: [0..7] = (lo,d) for is=0..3, [8] = sqrt(jfac), [9..11] pad
  __shared__ __align__(16) float lut[257][12];

  const int tid = threadIdx.x;

  for (int qi = tid; qi < 257; qi += TPB){
    const float q = (float)(qi - 128);
    const float w = (q * 0.0078125f) * 0.6f;
    #pragma unroll
    for (int is = 0; is < 4; ++is){
      const float* pl = poly_low  + is * 7;
      const float* ph = poly_high + is * 6;
      float lo = pl[6];
      lo = fmaf(lo, w, pl[5]); lo = fmaf(lo, w, pl[4]); lo = fmaf(lo, w, pl[3]);
      lo = fmaf(lo, w, pl[2]); lo = fmaf(lo, w, pl[1]); lo = fmaf(lo, w, pl[0]);
      float hi = ph[5];
      hi = fmaf(hi, w, ph[4]); hi = fmaf(hi, w, ph[3]); hi = fmaf(hi, w, ph[2]);
      hi = fmaf(hi, w, ph[1]); hi = fmaf(hi, w, ph[0]);
      lut[qi][is * 2]     = lo;
      lut[qi][is * 2 + 1] = hi - lo;
    }
    // sqrt(jfac): sigma = sqrt(|raw|) * sjf
    const float jf = fmaf(1.6567788e-28f,
                          __builtin_amdgcn_rcpf(fabsf(w) + 1e-12f),
                          5.4365637e-08f);
    lut[qi][8] = __builtin_amdgcn_sqrtf(jf);
  }
  __syncthreads();

  const int h = tid & 1;                    // k-half: adjacent lanes
  const int p = tid >> 1;
  const int gid = blockIdx.x * PPB + p;     // exact: grid*PPB == C*TOUT
  const int c = gid / TOUT;
  const int t = gid - c * TOUT;
  const int k0 = h ? 16 : 0;

  const uint32_t ka[4] = {nk0a, nk1a, nk2a, nk3a};
  const uint32_t kb[4] = {nk0b, nk1b, nk2b, nk3b};
  const uint32_t jbase = (uint32_t)((t * C_DIM + c) * KW);

  float acc[4][4];                          // [b][is]
  #pragma unroll
  for (int b = 0; b < 4; ++b)
    #pragma unroll
    for (int is = 0; is < 4; ++is) acc[b][is] = 0.0f;

  auto body = [&](int k){
    uint32_t qi[4];
    if (USE_WS){
      const uint2 ld = wsq[c * WSROW + t + k];
      qi[0] = ld.x & 0xFFFFu; qi[1] = ld.x >> 16;
      qi[2] = ld.y & 0xFFFFu; qi[3] = ld.y >> 16;
    } else {
      const int time = t + k - 15;
      const bool inb = (time >= 0) && (time < T_DIM);
      #pragma unroll
      for (int b = 0; b < 4; ++b){
        float xv = inb ? x[(b * C_DIM + c) * T_DIM + time] : 0.0f;
        float q = rintf(xv * 128.0f);
        q = fminf(fmaxf(q, -128.0f), 128.0f);
        qi[b] = (uint32_t)((int)q + 128);
      }
    }

    uint32_t bits[4];
    threefry_xor4(ka, kb, jbase + (uint32_t)k, bits);

    float noise[4];
    #pragma unroll
    for (int is = 0; is < 4; ++is){
      const float u1 = __uint_as_float((bits[is] >> 9) | 0x3f800000u) - 1.0f;
      const float uu = fmaxf(-0.99999994f, fmaf(u1, 2.0f, -0.99999994f));
      noise[is] = 1.41421356f * erfinv_fast(uu);
    }

    float rr[4];
    #pragma unroll
    for (int is = 0; is < 4; ++is)
      rr[is] = r[(is * C_DIM + c) * KW + k];

    #pragma unroll
    for (int b = 0; b < 4; ++b){
      const float* row = lut[qi[b]];
      const float4 A = *(const float4*)(row);      // lo0,d0,lo1,d1
      const float4 Bv = *(const float4*)(row + 4); // lo2,d2,lo3,d3
      const float sj = row[8];
      {
        const float raw = fmaf(A.y, rr[0], A.x);
        const float s = __builtin_amdgcn_sqrtf(fabsf(raw));
        acc[b][0] = fmaf(noise[0] * sj, s, acc[b][0] + raw);
      }
      {
        const float raw = fmaf(A.w, rr[1], A.z);
        const float s = __builtin_amdgcn_sqrtf(fabsf(raw));
        acc[b][1] = fmaf(noise[1] * sj, s, acc[b][1] + raw);
      }
      {
        const float raw = fmaf(Bv.y, rr[2], Bv.x);
        const float s = __builtin_amdgcn_sqrtf(fabsf(raw));
        acc[b][2] = fmaf(noise[2] * sj, s, acc[b][2] + raw);
      }
      {
        const float raw = fmaf(Bv.w, rr[3], Bv.z);
        const float s = __builtin_amdgcn_sqrtf(fabsf(raw));
        acc[b][3] = fmaf(noise[3] * sj, s, acc[b][3] + raw);
      }
    }
  };

  for (int kk = 0; kk < 15; ++kk) body(k0 + kk);
  if (h == 0) body(15);                     // even lanes own 16 k's (0..15)

  // combine the two k-halves: partner is the adjacent lane
  float tot[4][4];
  #pragma unroll
  for (int b = 0; b < 4; ++b)
    #pragma unroll
    for (int is = 0; is < 4; ++is)
      tot[b][is] = acc[b][is] + __shfl_xor(acc[b][is], 1);

  if (h == 0){
    const float bv = bias[c];
    #pragma unroll
    for (int b = 0; b < 4; ++b){
      float o = 0.0f;
      #pragma unroll
      for (int i = 0; i < 2; ++i){
        const float pair = tot[b][i*2+0] - tot[b][i*2+1];
        float q = rintf((pair * 8020.0f) * 256.0f);
        q = fminf(fmaxf(q, -131072.0f), 131072.0f);
        o += (q * 0.00390625f) * ((i == 0) ? 2.0f : 1.0f);
      }
      out[(b * C_DIM + c) * TOUT + t] = o + bv;
    }
  }
}

extern "C" void kernel_launch(void* const* d_in, const int* in_sizes, int n_in,
                              void* d_out, int out_size, void* d_ws, size_t ws_size,
                              hipStream_t stream) {
  const float* x         = (const float*)d_in[0];
  const float* poly_low  = (const float*)d_in[1];
  const float* poly_high = (const float*)d_in[2];
  const float* r         = (const float*)d_in[3];
  const float* bias      = (const float*)d_in[4];
  float* out             = (float*)d_out;

  // key chain: key = jax.random.key(42); 4x (key, nk) = split(key)
  uint32_t ck0 = 0u, ck1 = 42u;
  uint32_t nk[4][2];
  for (int n = 0; n < 4; ++n){
    uint32_t a0, a1, b0, b1;
    h_threefry2x32(ck0, ck1, 0u, 0u, &a0, &a1);  // new key
    h_threefry2x32(ck0, ck1, 0u, 1u, &b0, &b1);  // nk
    nk[n][0] = b0; nk[n][1] = b1;
    ck0 = a0; ck1 = a1;
  }

  const size_t ws_needed = (size_t)C_DIM * WSROW * 8;   // 1.77 MB
  const int nblocks = (C_DIM * TOUT) / PPB;             // 3200, exact

  if (ws_size >= ws_needed){
    uint2* wsq = (uint2*)d_ws;
    hipLaunchKernelGGL(dac_prepass, dim3((C_DIM * WSROW) / 256), dim3(256),
                       0, stream, x, wsq);
    hipLaunchKernelGGL((memristor_main<true>), dim3(nblocks), dim3(TPB), 0, stream,
                       x, poly_low, poly_high, r, bias, wsq, out,
                       nk[0][0], nk[0][1], nk[1][0], nk[1][1],
                       nk[2][0], nk[2][1], nk[3][0], nk[3][1]);
  } else {
    hipLaunchKernelGGL((memristor_main<false>), dim3(nblocks), dim3(TPB), 0, stream,
                       x, poly_low, poly_high, r, bias, (const uint2*)nullptr, out,
                       nk[0][0], nk[0][1], nk[1][0], nk[1][1],
                       nk[2][0], nk[2][1], nk[3][0], nk[3][1]);
  }
}

// Round 4
// 108.546 us; speedup vs baseline: 2.8065x; 1.0119x over previous
//
#include <hip/hip_runtime.h>
#include <cstdint>

#define C_DIM 512
#define T_DIM 400
#define KW 31
#define TOUT 400
#define WSROW 432        // padded time index t+k in [0,430] -> 432
#define TPB 512
#define PPB 128          // (c,t) pairs per block; 4 k-split lanes each
#define ROWB 48          // LUT row stride in bytes (12 floats)

#define WSQ_BYTES (C_DIM * WSROW * 8)        // 1,769,472
#define RT_OFF    WSQ_BYTES
#define RT_BYTES  (C_DIM * KW * 16)          // 253,952
#define WS_NEEDED (WSQ_BYTES + RT_BYTES)

// ---------------- host threefry2x32 (key-chain computation, pure CPU) --------
static inline uint32_t h_rotl32(uint32_t x, int d){ return (x<<d)|(x>>(32-d)); }

static void h_threefry2x32(uint32_t k0, uint32_t k1, uint32_t x0, uint32_t x1,
                           uint32_t* o0, uint32_t* o1){
  uint32_t ks2 = k0 ^ k1 ^ 0x1BD11BDAu;
  uint32_t ks[3] = {k0, k1, ks2};
  const int rotA[4] = {13,15,26,6};
  const int rotB[4] = {17,29,16,24};
  uint32_t v0 = x0 + k0, v1 = x1 + k1;
  for (int r = 0; r < 5; ++r){
    const int* rot = (r & 1) ? rotB : rotA;
    for (int q = 0; q < 4; ++q){
      v0 += v1; v1 = h_rotl32(v1, rot[q]); v1 ^= v0;
    }
    v0 += ks[(r+1)%3];
    v1 += ks[(r+2)%3] + (uint32_t)(r+1);
  }
  *o0 = v0; *o1 = v1;
}

// ---------------- device threefry, 4 independent streams in lockstep --------
template<int R>
__device__ __forceinline__ void tfr4(uint32_t v0[4], uint32_t v1[4]){
  #pragma unroll
  for (int n = 0; n < 4; ++n){
    v0[n] += v1[n];
    v1[n] = (v1[n] << R) | (v1[n] >> (32 - R));   // -> v_alignbit_b32
    v1[n] ^= v0[n];
  }
}

__device__ __forceinline__ void tfinj4(uint32_t v0[4], uint32_t v1[4],
                                       const uint32_t a[4], const uint32_t b[4],
                                       uint32_t cadd){
  #pragma unroll
  for (int n = 0; n < 4; ++n){ v0[n] += a[n]; v1[n] += b[n] + cadd; }
}

__device__ __forceinline__ void threefry_xor4(const uint32_t ka[4], const uint32_t kb[4],
                                              uint32_t j, uint32_t out[4]){
  uint32_t ks2[4], v0[4], v1[4];
  #pragma unroll
  for (int n = 0; n < 4; ++n){
    ks2[n] = ka[n] ^ kb[n] ^ 0x1BD11BDAu;
    v0[n] = ka[n];            // x0 = 0
    v1[n] = j + kb[n];        // x1 = j
  }
  tfr4<13>(v0,v1); tfr4<15>(v0,v1); tfr4<26>(v0,v1); tfr4<6>(v0,v1);
  tfinj4(v0,v1,kb,ks2,1u);
  tfr4<17>(v0,v1); tfr4<29>(v0,v1); tfr4<16>(v0,v1); tfr4<24>(v0,v1);
  tfinj4(v0,v1,ks2,ka,2u);
  tfr4<13>(v0,v1); tfr4<15>(v0,v1); tfr4<26>(v0,v1); tfr4<6>(v0,v1);
  tfinj4(v0,v1,ka,kb,3u);
  tfr4<17>(v0,v1); tfr4<29>(v0,v1); tfr4<16>(v0,v1); tfr4<24>(v0,v1);
  tfinj4(v0,v1,kb,ks2,4u);
  tfr4<13>(v0,v1); tfr4<15>(v0,v1); tfr4<26>(v0,v1); tfr4<6>(v0,v1);
  tfinj4(v0,v1,ks2,ka,5u);
  #pragma unroll
  for (int n = 0; n < 4; ++n) out[n] = v0[n] ^ v1[n];
}

// -------- XLA ErfInv32 (Giles 2012), raw-rate v_log / v_sqrt ----------------
__device__ __forceinline__ float erfinv_fast(float x){
  // -log1p(-x^2) = -ln2 * log2((1-x)(1+x))
  float w = -0.69314718f * __builtin_amdgcn_logf((1.0f - x) * (1.0f + x));
  float p;
  if (w < 5.0f){
    w = w - 2.5f;
    p =              2.81022636e-08f;
    p = fmaf(p, w,   3.43273939e-07f);
    p = fmaf(p, w,  -3.5233877e-06f);
    p = fmaf(p, w,  -4.39150654e-06f);
    p = fmaf(p, w,   0.00021858087f);
    p = fmaf(p, w,  -0.00125372503f);
    p = fmaf(p, w,  -0.00417768164f);
    p = fmaf(p, w,   0.246640727f);
    p = fmaf(p, w,   1.50140941f);
  } else {
    w = __builtin_amdgcn_sqrtf(w) - 3.0f;
    p =             -0.000200214257f;
    p = fmaf(p, w,   0.000100950558f);
    p = fmaf(p, w,   0.00134934322f);
    p = fmaf(p, w,  -0.00367342844f);
    p = fmaf(p, w,   0.00573950773f);
    p = fmaf(p, w,  -0.0076224613f);
    p = fmaf(p, w,   0.00943887047f);
    p = fmaf(p, w,   1.00167406f);
    p = fmaf(p, w,   2.83297682f);
  }
  return p * x;
}

// ------- pre-pass 1: DAC-quantize x once per (c,time), store LDS byte offs --
__global__ __launch_bounds__(256) void dac_prepass(
    const float* __restrict__ x, uint2* __restrict__ wsq)
{
  const int m = blockIdx.x * 256 + threadIdx.x;      // exact over C_DIM*WSROW
  const int c  = m / WSROW;
  const int tp = m - c * WSROW;
  const int time = tp - 15;
  const bool inb = (time >= 0) && (time < T_DIM);
  uint32_t off[4];
  #pragma unroll
  for (int b = 0; b < 4; ++b){
    float xv = inb ? x[(b * C_DIM + c) * T_DIM + time] : 0.0f;
    float q = rintf(xv * 128.0f);
    q = fminf(fmaxf(q, -128.0f), 128.0f);
    off[b] = (uint32_t)(((int)q + 128) * ROWB);      // LDS byte offset
  }
  wsq[m] = make_uint2(off[0] | (off[1] << 16), off[2] | (off[3] << 16));
}

// ------- pre-pass 2: transpose r to (c, k, is) float4 -----------------------
__global__ __launch_bounds__(256) void r_prepass(
    const float* __restrict__ r, float4* __restrict__ rT)
{
  const int m = blockIdx.x * 256 + threadIdx.x;      // over C_DIM*KW
  if (m >= C_DIM * KW) return;
  const int c = m / KW;
  const int k = m - c * KW;
  float4 v;
  v.x = r[(0 * C_DIM + c) * KW + k];
  v.y = r[(1 * C_DIM + c) * KW + k];
  v.z = r[(2 * C_DIM + c) * KW + k];
  v.w = r[(3 * C_DIM + c) * KW + k];
  rT[m] = v;
}

// ---------------- main kernel ----------------------------------------------
template<bool USE_WS>
__global__ __launch_bounds__(TPB) void memristor_main(
    const float* __restrict__ x,
    const float* __restrict__ poly_low,   // (2,2,7)
    const float* __restrict__ poly_high,  // (2,2,6)
    const float* __restrict__ r,          // (2,2,C,K)
    const float* __restrict__ bias,
    const uint2* __restrict__ wsq,        // (C, WSROW) packed u16 byte-offs x4
    const float4* __restrict__ rT,        // (C, K) -> (r0,r1,r2,r3)
    float* __restrict__ out,              // (B,C,TOUT)
    uint32_t nk0a, uint32_t nk0b, uint32_t nk1a, uint32_t nk1b,
    uint32_t nk2a, uint32_t nk2b, uint32_t nk3a, uint32_t nk3b)
{
  // flat LUT, row = 12 floats: [0..7]=(lo,d) is=0..3, [8]=sqrt(jfac), pad 3
  __shared__ __align__(16) float lut[257 * 12];

  const int tid = threadIdx.x;

  if (tid < 257){
    const int qi = tid;
    const float q = (float)(qi - 128);
    const float w = (q * 0.0078125f) * 0.6f;
    #pragma unroll
    for (int is = 0; is < 4; ++is){
      const float* pl = poly_low  + is * 7;
      const float* ph = poly_high + is * 6;
      float lo = pl[6];
      lo = fmaf(lo, w, pl[5]); lo = fmaf(lo, w, pl[4]); lo = fmaf(lo, w, pl[3]);
      lo = fmaf(lo, w, pl[2]); lo = fmaf(lo, w, pl[1]); lo = fmaf(lo, w, pl[0]);
      float hi = ph[5];
      hi = fmaf(hi, w, ph[4]); hi = fmaf(hi, w, ph[3]); hi = fmaf(hi, w, ph[2]);
      hi = fmaf(hi, w, ph[1]); hi = fmaf(hi, w, ph[0]);
      lut[qi * 12 + is * 2]     = lo;
      lut[qi * 12 + is * 2 + 1] = hi - lo;
    }
    const float jf = fmaf(1.6567788e-28f,
                          __builtin_amdgcn_rcpf(fabsf(w) + 1e-12f),
                          5.4365637e-08f);
    lut[qi * 12 + 8] = __builtin_amdgcn_sqrtf(jf);
  }
  __syncthreads();

  // 4 lanes per (c,t): lane l covers k in [8l, min(8l+8, 31))
  const int l   = tid & 3;
  const int p   = tid >> 2;
  const int gid = blockIdx.x * PPB + p;     // exact: grid*PPB == C*TOUT
  const int c   = gid / TOUT;
  const int t   = gid - c * TOUT;
  const int k0  = l * 8;
  const int kn  = (l == 3) ? 7 : 8;

  const uint32_t ka[4] = {nk0a, nk1a, nk2a, nk3a};
  const uint32_t kb[4] = {nk0b, nk1b, nk2b, nk3b};
  const uint32_t jbase = (uint32_t)((t * C_DIM + c) * KW);

  float acc[4][4];                          // [b][is]
  #pragma unroll
  for (int b = 0; b < 4; ++b)
    #pragma unroll
    for (int is = 0; is < 4; ++is) acc[b][is] = 0.0f;

  for (int kk = 0; kk < kn; ++kk){
    const int k = k0 + kk;

    uint32_t off[4];
    float4 rv;
    if (USE_WS){
      const uint2 ld = wsq[c * WSROW + t + k];
      off[0] = ld.x & 0xFFFFu; off[1] = ld.x >> 16;
      off[2] = ld.y & 0xFFFFu; off[3] = ld.y >> 16;
      rv = rT[c * KW + k];
    } else {
      const int time = t + k - 15;
      const bool inb = (time >= 0) && (time < T_DIM);
      #pragma unroll
      for (int b = 0; b < 4; ++b){
        float xv = inb ? x[(b * C_DIM + c) * T_DIM + time] : 0.0f;
        float q = rintf(xv * 128.0f);
        q = fminf(fmaxf(q, -128.0f), 128.0f);
        off[b] = (uint32_t)(((int)q + 128) * ROWB);
      }
      rv.x = r[(0 * C_DIM + c) * KW + k];
      rv.y = r[(1 * C_DIM + c) * KW + k];
      rv.z = r[(2 * C_DIM + c) * KW + k];
      rv.w = r[(3 * C_DIM + c) * KW + k];
    }

    uint32_t bits[4];
    threefry_xor4(ka, kb, jbase + (uint32_t)k, bits);

    float noise[4];
    #pragma unroll
    for (int is = 0; is < 4; ++is){
      const float u1 = __uint_as_float((bits[is] >> 9) | 0x3f800000u) - 1.0f;
      const float uu = fmaxf(-0.99999994f, fmaf(u1, 2.0f, -0.99999994f));
      noise[is] = 1.41421356f * erfinv_fast(uu);
    }

    #pragma unroll
    for (int b = 0; b < 4; ++b){
      const float* row = (const float*)((const char*)lut + off[b]);
      const float4 A  = *(const float4*)(row);      // lo0,d0,lo1,d1
      const float4 Bv = *(const float4*)(row + 4);  // lo2,d2,lo3,d3
      const float sj  = row[8];
      {
        const float raw = fmaf(A.y, rv.x, A.x);
        const float s = __builtin_amdgcn_sqrtf(fabsf(raw));
        acc[b][0] = fmaf(noise[0] * sj, s, acc[b][0] + raw);
      }
      {
        const float raw = fmaf(A.w, rv.y, A.z);
        const float s = __builtin_amdgcn_sqrtf(fabsf(raw));
        acc[b][1] = fmaf(noise[1] * sj, s, acc[b][1] + raw);
      }
      {
        const float raw = fmaf(Bv.y, rv.z, Bv.x);
        const float s = __builtin_amdgcn_sqrtf(fabsf(raw));
        acc[b][2] = fmaf(noise[2] * sj, s, acc[b][2] + raw);
      }
      {
        const float raw = fmaf(Bv.w, rv.w, Bv.z);
        const float s = __builtin_amdgcn_sqrtf(fabsf(raw));
        acc[b][3] = fmaf(noise[3] * sj, s, acc[b][3] + raw);
      }
    }
  }

  // quad butterfly combine (DPP quad_perm): every lane ends with full sums
  float tot[4][4];
  #pragma unroll
  for (int b = 0; b < 4; ++b)
    #pragma unroll
    for (int is = 0; is < 4; ++is){
      float v = acc[b][is];
      v += __shfl_xor(v, 1);
      v += __shfl_xor(v, 2);
      tot[b][is] = v;
    }

  if (l == 0){
    const float bv = bias[c];
    #pragma unroll
    for (int b = 0; b < 4; ++b){
      float o = 0.0f;
      #pragma unroll
      for (int i = 0; i < 2; ++i){
        const float pair = tot[b][i*2+0] - tot[b][i*2+1];
        float q = rintf((pair * 8020.0f) * 256.0f);
        q = fminf(fmaxf(q, -131072.0f), 131072.0f);
        o += (q * 0.00390625f) * ((i == 0) ? 2.0f : 1.0f);
      }
      out[(b * C_DIM + c) * TOUT + t] = o + bv;
    }
  }
}

extern "C" void kernel_launch(void* const* d_in, const int* in_sizes, int n_in,
                              void* d_out, int out_size, void* d_ws, size_t ws_size,
                              hipStream_t stream) {
  const float* x         = (const float*)d_in[0];
  const float* poly_low  = (const float*)d_in[1];
  const float* poly_high = (const float*)d_in[2];
  const float* r         = (const float*)d_in[3];
  const float* bias      = (const float*)d_in[4];
  float* out             = (float*)d_out;

  // key chain: key = jax.random.key(42); 4x (key, nk) = split(key)
  uint32_t ck0 = 0u, ck1 = 42u;
  uint32_t nk[4][2];
  for (int n = 0; n < 4; ++n){
    uint32_t a0, a1, b0, b1;
    h_threefry2x32(ck0, ck1, 0u, 0u, &a0, &a1);  // new key
    h_threefry2x32(ck0, ck1, 0u, 1u, &b0, &b1);  // nk
    nk[n][0] = b0; nk[n][1] = b1;
    ck0 = a0; ck1 = a1;
  }

  const int nblocks = (C_DIM * TOUT) / PPB;      // 1600, exact

  if (ws_size >= (size_t)WS_NEEDED){
    uint2*  wsq = (uint2*)d_ws;
    float4* rT  = (float4*)((char*)d_ws + RT_OFF);
    hipLaunchKernelGGL(dac_prepass, dim3((C_DIM * WSROW) / 256), dim3(256),
                       0, stream, x, wsq);
    hipLaunchKernelGGL(r_prepass, dim3((C_DIM * KW + 255) / 256), dim3(256),
                       0, stream, r, rT);
    hipLaunchKernelGGL((memristor_main<true>), dim3(nblocks), dim3(TPB), 0, stream,
                       x, poly_low, poly_high, r, bias, wsq, rT, out,
                       nk[0][0], nk[0][1], nk[1][0], nk[1][1],
                       nk[2][0], nk[2][1], nk[3][0], nk[3][1]);
  } else {
    hipLaunchKernelGGL((memristor_main<false>), dim3(nblocks), dim3(TPB), 0, stream,
                       x, poly_low, poly_high, r, bias,
                       (const uint2*)nullptr, (const float4*)nullptr, out,
                       nk[0][0], nk[0][1], nk[1][0], nk[1][1],
                       nk[2][0], nk[2][1], nk[3][0], nk[3][1]);
  }
}